// Round 5
// baseline (490.138 us; speedup 1.0000x reference)
//
#include <hip/hip_runtime.h>
#include <hip/hip_bf16.h>

#define SEQ   2048
#define NH    16
#define DK    64
#define DM    1024
#define NTOK  4096
#define C1    0.1803368801111204f   // 0.125 * log2(e)

typedef unsigned short u16;
typedef unsigned int   u32;
typedef short bhalf8 __attribute__((ext_vector_type(8)));   // 8 bf16 = 4 VGPRs
typedef float floatx4 __attribute__((ext_vector_type(4)));  // MFMA acc

#define MFMA16(a,b,c) __builtin_amdgcn_mfma_f32_16x16x32_bf16(a,b,c,0,0,0)

// fp32 -> bf16 round-to-nearest-even
__device__ __forceinline__ u16 f2b(float f){
  union { float f; u32 u; } v; v.f = f;
  u32 r = v.u + 0x7fffu + ((v.u >> 16) & 1u);
  return (u16)(r >> 16);
}
__device__ __forceinline__ u32 pack2(float a, float b){
  return (u32)f2b(a) | ((u32)f2b(b) << 16);
}
__device__ __forceinline__ bhalf8 pk8(const float4 f0, const float4 f1){
  union { bhalf8 h; u32 w[4]; } o;
  o.w[0] = pack2(f0.x, f0.y); o.w[1] = pack2(f0.z, f0.w);
  o.w[2] = pack2(f1.x, f1.y); o.w[3] = pack2(f1.z, f1.w);
  return o.h;
}

// ---------------------------------------------------------------------------
// Transpose + convert: W fp32 [k][n] (1024x1024) -> Wt bf16 [n][k]
// ---------------------------------------------------------------------------
__global__ __launch_bounds__(256)
void wtrans(const float* __restrict__ W, u16* __restrict__ Wt)
{
  __shared__ __align__(16) u16 T[64][68];
  const int k0 = blockIdx.y * 64, n0 = blockIdx.x * 64;
  const int t = threadIdx.x;
  #pragma unroll
  for (int p = 0; p < 16; ++p){
    int e = p*256 + t, k = e >> 6, n = e & 63;
    T[n][k] = f2b(W[(size_t)(k0+k)*DM + n0 + n]);
  }
  __syncthreads();
  #pragma unroll
  for (int p = 0; p < 8; ++p){
    int e = p*256 + t, n = e >> 5, kp = e & 31;
    u32 val = *(const u32*)&T[n][2*kp];
    *(u32*)&Wt[(size_t)(n0+n)*DM + k0 + 2*kp] = val;
  }
}

// ---------------------------------------------------------------------------
// Direct-register MFMA GEMM: C[m][n] = (sum_k A[m][k]*Wt[n][k] + bias[n]) * X
// 128x128 block, 4 waves as 2x2 of 64x64. No LDS; frags direct from global,
// software prefetch depth 2.
// AFP32: A is fp32 (converted in registers) else bf16.
// OMODE: 0 = bf16 C[m][DM] scaled by cmul
//        1 = bf16 Vt[((b*NH+h)*DK+d)*SEQ + s], scaled by Linv[bh][s]
//        2 = fp32 C[m][DM]
// ---------------------------------------------------------------------------
template<int AFP32, int OMODE>
__global__ __launch_bounds__(256)
void gemm_direct(const void* __restrict__ Ap, const u16* __restrict__ Wt,
                 const float* __restrict__ bias, const float* __restrict__ Linv,
                 void* __restrict__ Cp, float cmul)
{
  const int bm = blockIdx.y * 128, bn = blockIdx.x * 128;
  const int t = threadIdx.x, wid = t >> 6, l = t & 63, r16 = l & 15, q = l >> 4;
  const int wm = (wid & 1) * 64, wn = (wid >> 1) * 64;
  floatx4 acc[4][4] = {};

  const u16*   Ab16 = (const u16*)Ap   + (size_t)(bm + wm + r16)*DM + q*8;
  const float* Ab32 = (const float*)Ap + (size_t)(bm + wm + r16)*DM + q*8;
  const u16*   Bb   = Wt + (size_t)(bn + wn + r16)*DM + q*8;

  bhalf8 af0[4], bf0[4], af1[4], bf1[4];
  #pragma unroll
  for (int i = 0; i < 4; ++i){
    if (AFP32){
      af0[i] = pk8(*(const float4*)(Ab32 + (size_t)i*16*DM),
                   *(const float4*)(Ab32 + (size_t)i*16*DM + 4));
      af1[i] = pk8(*(const float4*)(Ab32 + (size_t)i*16*DM + 32),
                   *(const float4*)(Ab32 + (size_t)i*16*DM + 36));
    } else {
      af0[i] = *(const bhalf8*)(Ab16 + (size_t)i*16*DM);
      af1[i] = *(const bhalf8*)(Ab16 + (size_t)i*16*DM + 32);
    }
  }
  #pragma unroll
  for (int j = 0; j < 4; ++j){
    bf0[j] = *(const bhalf8*)(Bb + (size_t)j*16*DM);
    bf1[j] = *(const bhalf8*)(Bb + (size_t)j*16*DM + 32);
  }

  #pragma unroll
  for (int kc = 0; kc < DM; kc += 32){
    const int kn = (kc + 64 < DM) ? (kc + 64) : (DM - 32);   // clamped prefetch
    bhalf8 afn[4], bfn[4];
    #pragma unroll
    for (int i = 0; i < 4; ++i){
      if (AFP32)
        afn[i] = pk8(*(const float4*)(Ab32 + (size_t)i*16*DM + kn),
                     *(const float4*)(Ab32 + (size_t)i*16*DM + kn + 4));
      else
        afn[i] = *(const bhalf8*)(Ab16 + (size_t)i*16*DM + kn);
    }
    #pragma unroll
    for (int j = 0; j < 4; ++j)
      bfn[j] = *(const bhalf8*)(Bb + (size_t)j*16*DM + kn);

    #pragma unroll
    for (int i = 0; i < 4; ++i)
      #pragma unroll
      for (int j = 0; j < 4; ++j)
        acc[i][j] = MFMA16(af0[i], bf0[j], acc[i][j]);

    #pragma unroll
    for (int i = 0; i < 4; ++i){ af0[i] = af1[i]; af1[i] = afn[i]; }
    #pragma unroll
    for (int j = 0; j < 4; ++j){ bf0[j] = bf1[j]; bf1[j] = bfn[j]; }
  }

  // epilogue: D row = wm+i*16+q*4+r, col = wn+j*16+r16 (within block)
  if (OMODE == 0){
    u16* C = (u16*)Cp;
    #pragma unroll
    for (int j = 0; j < 4; ++j){
      const int n = bn + wn + j*16 + r16;
      const float bj = bias[n];
      #pragma unroll
      for (int i = 0; i < 4; ++i){
        const int m0 = bm + wm + i*16 + q*4;
        #pragma unroll
        for (int r = 0; r < 4; ++r)
          C[(size_t)(m0+r)*DM + n] = f2b((acc[i][j][r] + bj) * cmul);
      }
    }
  } else if (OMODE == 1){
    u16* C = (u16*)Cp;
    const int h  = (bn + wn) >> 6;           // one head per wave (wn 64-aligned)
    const int bb = (bm + wm) >> 11;
    const int s0 = (bm + wm) & (SEQ - 1);
    #pragma unroll
    for (int i = 0; i < 4; ++i){
      const int sl = s0 + i*16 + q*4;
      const float4 sc = *(const float4*)(Linv + (size_t)(bb*NH + h)*SEQ + sl);
      #pragma unroll
      for (int j = 0; j < 4; ++j){
        const int d = j*16 + r16;
        const float bj = bias[h*DK + d];
        u32 v0 = pack2((acc[i][j][0]+bj)*sc.x, (acc[i][j][1]+bj)*sc.y);
        u32 v1 = pack2((acc[i][j][2]+bj)*sc.z, (acc[i][j][3]+bj)*sc.w);
        *(uint2*)&C[((size_t)(bb*NH + h)*DK + d)*SEQ + sl] = make_uint2(v0, v1);
      }
    }
  } else {
    float* C = (float*)Cp;
    #pragma unroll
    for (int j = 0; j < 4; ++j){
      const int n = bn + wn + j*16 + r16;
      const float bj = bias[n];
      #pragma unroll
      for (int i = 0; i < 4; ++i){
        const int m0 = bm + wm + i*16 + q*4;
        #pragma unroll
        for (int r = 0; r < 4; ++r)
          C[(size_t)(m0+r)*DM + n] = acc[i][j][r] + bj;
      }
    }
  }
}

// ---------------------------------------------------------------------------
// Stats: Linv[bh][j] = 1 / sum_i 2^(s'_ij).  No max needed (|s'| < ~4).
// Block = (64-wide j tile, bh). K-frags in regs, Q-frags direct global.
// Barrier-free except final cross-wave combine.
// ---------------------------------------------------------------------------
__global__ __launch_bounds__(256)
void attn_stats(const u16* __restrict__ Qb, const u16* __restrict__ Kb,
                float* __restrict__ Linv)
{
  __shared__ float pl[4][64];
  const int j0 = blockIdx.x * 64, bh = blockIdx.y, b = bh >> 4, h = bh & 15;
  const int t = threadIdx.x, wid = t >> 6, l = t & 63, r16 = l & 15, q = l >> 4;

  bhalf8 kf[4][2];
  const u16* kp = Kb + (size_t)(b*SEQ + j0 + r16)*DM + h*DK + q*8;
  #pragma unroll
  for (int st = 0; st < 4; ++st){
    kf[st][0] = *(const bhalf8*)(kp + (size_t)st*16*DM);
    kf[st][1] = *(const bhalf8*)(kp + (size_t)st*16*DM + 32);
  }
  float rl[4] = {0.f, 0.f, 0.f, 0.f};
  const u16* qp = Qb + (size_t)(b*SEQ + wid*16 + r16)*DM + h*DK + q*8;
  for (int it = 0; it < SEQ/64; ++it){
    bhalf8 qf0 = *(const bhalf8*)qp;
    bhalf8 qf1 = *(const bhalf8*)(qp + 32);
    qp += (size_t)64*DM;
    #pragma unroll
    for (int st = 0; st < 4; ++st){
      floatx4 s = {};
      s = MFMA16(qf0, kf[st][0], s);
      s = MFMA16(qf1, kf[st][1], s);
      rl[st] += exp2f(s[0]) + exp2f(s[1]) + exp2f(s[2]) + exp2f(s[3]);
    }
  }
  #pragma unroll
  for (int st = 0; st < 4; ++st){
    float v = rl[st];
    v += __shfl_xor(v, 16);
    v += __shfl_xor(v, 32);
    rl[st] = v;
  }
  if (q == 0){
    #pragma unroll
    for (int st = 0; st < 4; ++st) pl[wid][st*16 + r16] = rl[st];
  }
  __syncthreads();
  if (t < 64)
    Linv[(size_t)bh*SEQ + j0 + t] = 1.f / (pl[0][t] + pl[1][t] + pl[2][t] + pl[3][t]);
}

// ---------------------------------------------------------------------------
// PV: X[i][d] = sum_j 2^(s'_ij) * V'[j][d]   (V' pre-scaled by Linv)
// S^T trick: MFMA(K,Q) -> D[j][i]; lane holds 4 consecutive j -> b64 P-writes.
// K/V double-buffered LDS with register prefetch; Q-frags direct global.
// ---------------------------------------------------------------------------
__global__ __launch_bounds__(256)
void attn_pv(const u16* __restrict__ Qb, const u16* __restrict__ Kb,
             const u16* __restrict__ Vt, u16* __restrict__ Xb)
{
  __shared__ __align__(16) u16 Kls[2][64][72];
  __shared__ __align__(16) u16 Vls[2][64][72];
  __shared__ __align__(16) u16 Pls[64][72];
  const int i0 = blockIdx.x * 64, bh = blockIdx.y, b = bh >> 4, h = bh & 15;
  const int t = threadIdx.x, wid = t >> 6, l = t & 63, r16 = l & 15, q = l >> 4;
  const int sr = t >> 2, sc = t & 3;

  const u16* qp = Qb + (size_t)(b*SEQ + i0 + wid*16 + r16)*DM + h*DK + q*8;
  const bhalf8 qf0 = *(const bhalf8*)qp;
  const bhalf8 qf1 = *(const bhalf8*)(qp + 32);

  const u16* krow = Kb + (size_t)(b*SEQ + sr)*DM + h*DK;   // + j0*DM per tile
  const u16* vrow = Vt + ((size_t)bh*DK + sr)*SEQ;         // + j0 per tile
  {
    *(uint4*)&Kls[0][sr][sc*8]      = *(const uint4*)(krow + sc*8);
    *(uint4*)&Kls[0][sr][sc*8 + 32] = *(const uint4*)(krow + sc*8 + 32);
    *(uint4*)&Vls[0][sr][sc*8]      = *(const uint4*)(vrow + sc*8);
    *(uint4*)&Vls[0][sr][sc*8 + 32] = *(const uint4*)(vrow + sc*8 + 32);
  }
  __syncthreads();

  floatx4 xacc[4] = {};
  for (int jt = 0; jt < SEQ/64; ++jt){
    const int p = jt & 1;
    // prefetch next K/V tile into registers (clamped; jt=31 dup is harmless)
    const int jn = (jt + 1 < SEQ/64) ? (jt + 1) : (SEQ/64 - 1);
    const u16* ks = krow + (size_t)jn*64*DM;
    const u16* vs = vrow + jn*64;
    uint4 sK0 = *(const uint4*)(ks + sc*8);
    uint4 sK1 = *(const uint4*)(ks + sc*8 + 32);
    uint4 sV0 = *(const uint4*)(vs + sc*8);
    uint4 sV1 = *(const uint4*)(vs + sc*8 + 32);

    // S^T: A = K-frag (j rows), B = Q-frag (i cols). P = 2^s' -> Pls[i][j]
    #pragma unroll
    for (int st = 0; st < 4; ++st){
      bhalf8 k0 = *(const bhalf8*)&Kls[p][st*16 + r16][q*8];
      bhalf8 k1 = *(const bhalf8*)&Kls[p][st*16 + r16][32 + q*8];
      floatx4 s = {};
      s = MFMA16(k0, qf0, s);
      s = MFMA16(k1, qf1, s);
      u32 lo = pack2(exp2f(s[0]), exp2f(s[1]));
      u32 hi = pack2(exp2f(s[2]), exp2f(s[3]));
      *(uint2*)&Pls[wid*16 + r16][st*16 + q*4] = make_uint2(lo, hi);
    }
    __syncthreads();   // P visible

    bhalf8 pf0 = *(const bhalf8*)&Pls[wid*16 + r16][q*8];
    bhalf8 pf1 = *(const bhalf8*)&Pls[wid*16 + r16][32 + q*8];
    #pragma unroll
    for (int dst = 0; dst < 4; ++dst){
      bhalf8 v0 = *(const bhalf8*)&Vls[p][dst*16 + r16][q*8];
      bhalf8 v1 = *(const bhalf8*)&Vls[p][dst*16 + r16][32 + q*8];
      xacc[dst] = MFMA16(pf0, v0, xacc[dst]);
      xacc[dst] = MFMA16(pf1, v1, xacc[dst]);
    }
    // commit prefetched tile to the other buffer
    *(uint4*)&Kls[p^1][sr][sc*8]      = sK0;
    *(uint4*)&Kls[p^1][sr][sc*8 + 32] = sK1;
    *(uint4*)&Vls[p^1][sr][sc*8]      = sV0;
    *(uint4*)&Vls[p^1][sr][sc*8 + 32] = sV1;
    __syncthreads();   // staged buffer ready; P reads done
  }

  #pragma unroll
  for (int dst = 0; dst < 4; ++dst)
    #pragma unroll
    for (int r = 0; r < 4; ++r)
      Xb[(size_t)(b*SEQ + i0 + wid*16 + q*4 + r)*DM + h*DK + dst*16 + r16]
        = f2b(xacc[dst][r]);
}

// ---------------------------------------------------------------------------
extern "C" void kernel_launch(void* const* d_in, const int* in_sizes, int n_in,
                              void* d_out, int out_size, void* d_ws, size_t ws_size,
                              hipStream_t stream)
{
  const float* q  = (const float*)d_in[0];
  const float* k  = (const float*)d_in[1];
  const float* v  = (const float*)d_in[2];
  const float* Wq = (const float*)d_in[3];
  const float* bq = (const float*)d_in[4];
  const float* Wk = (const float*)d_in[5];
  const float* bk = (const float*)d_in[6];
  const float* Wv = (const float*)d_in[7];
  const float* bv = (const float*)d_in[8];
  const float* Wo = (const float*)d_in[9];
  const float* bo = (const float*)d_in[10];
  float* out = (float*)d_out;

  // ws: [Linv 256K][Wtq|Wtk|Wtv|Wto 2MB each][Qb 8M][Kb 8M][Vt 8M][Xb 8M] = 40.5 MiB
  char* ws = (char*)d_ws;
  const size_t STATB = (size_t)NH * 2 * SEQ * sizeof(float);   // 256 KiB
  const size_t WTB   = (size_t)DM * DM * sizeof(u16);          // 2 MiB
  const size_t TOKB  = (size_t)NTOK * DM * sizeof(u16);        // 8 MiB
  float* Linv = (float*)(ws);
  u16*   Wtq  = (u16*)(ws + STATB);
  u16*   Wtk  = (u16*)(ws + STATB + WTB);
  u16*   Wtv  = (u16*)(ws + STATB + 2*WTB);
  u16*   Wto  = (u16*)(ws + STATB + 3*WTB);
  u16*   Qb   = (u16*)(ws + STATB + 4*WTB);
  u16*   Kb   = (u16*)(ws + STATB + 4*WTB + TOKB);
  u16*   Vt   = (u16*)(ws + STATB + 4*WTB + 2*TOKB);
  u16*   Xb   = (u16*)(ws + STATB + 4*WTB + 3*TOKB);

  dim3 blk(256);
  dim3 gt(16, 16);
  wtrans<<<gt, blk, 0, stream>>>(Wq, Wtq);
  wtrans<<<gt, blk, 0, stream>>>(Wk, Wtk);
  wtrans<<<gt, blk, 0, stream>>>(Wv, Wtv);
  wtrans<<<gt, blk, 0, stream>>>(Wo, Wto);

  dim3 gg(DM/128, NTOK/128);   // (8, 32)
  // Q projection pre-scaled by 0.125*log2(e); K plain.
  gemm_direct<1,0><<<gg, blk, 0, stream>>>(q, Wtq, bq, nullptr, Qb, C1);
  gemm_direct<1,0><<<gg, blk, 0, stream>>>(k, Wtk, bk, nullptr, Kb, 1.0f);

  dim3 ga(SEQ/64, NH*2);       // (32, 32)
  attn_stats<<<ga, blk, 0, stream>>>(Qb, Kb, Linv);

  // V projection: transposed output, scaled by Linv (softmax denominator folded in)
  gemm_direct<1,1><<<gg, blk, 0, stream>>>(v, Wtv, bv, Linv, Vt, 1.0f);

  attn_pv<<<ga, blk, 0, stream>>>(Qb, Kb, Vt, Xb);

  gemm_direct<0,2><<<gg, blk, 0, stream>>>(Xb, Wto, bo, nullptr, out, 1.0f);
}

// Round 6
// 352.801 us; speedup vs baseline: 1.3893x; 1.3893x over previous
//
#include <hip/hip_runtime.h>
#include <hip/hip_bf16.h>

#define SEQ   2048
#define NH    16
#define DK    64
#define DM    1024
#define NTOK  4096
#define C1    0.1803368801111204f   // 0.125 * log2(e)

typedef unsigned short u16;
typedef unsigned int   u32;
typedef short bhalf8 __attribute__((ext_vector_type(8)));   // 8 bf16 = 4 VGPRs
typedef float floatx4 __attribute__((ext_vector_type(4)));  // MFMA acc

#define MFMA16(a,b,c) __builtin_amdgcn_mfma_f32_16x16x32_bf16(a,b,c,0,0,0)

// fp32 -> bf16 round-to-nearest-even (scalar fallback path)
__device__ __forceinline__ u16 f2b(float f){
  union { float f; u32 u; } v; v.f = f;
  u32 r = v.u + 0x7fffu + ((v.u >> 16) & 1u);
  return (u16)(r >> 16);
}
// packed fp32x2 -> bf16x2 (RNE) via HIP API (HW packed cvt where available)
__device__ __forceinline__ u32 pk2(float a, float b){
  union { __hip_bfloat162 h; u32 w; } o;
  o.h = __float22bfloat162_rn(make_float2(a, b));
  return o.w;
}

// async global->LDS, 16B per lane; lds base must be wave-uniform
__device__ __forceinline__ void gld_lds16(const u16* g, u16* lds){
  __builtin_amdgcn_global_load_lds(
      (const __attribute__((address_space(1))) u32*)g,
      (__attribute__((address_space(3))) u32*)lds, 16, 0, 0);
}

// ---------------------------------------------------------------------------
// fp32 -> bf16 convert (memory-bound), 8 elems/thread
// ---------------------------------------------------------------------------
__global__ __launch_bounds__(256)
void cvt_bf16(const float* __restrict__ in, u16* __restrict__ out)
{
  const size_t i = ((size_t)blockIdx.x * 256 + threadIdx.x) * 8;
  const float4 a = *(const float4*)(in + i);
  const float4 b = *(const float4*)(in + i + 4);
  uint4 o;
  o.x = pk2(a.x, a.y); o.y = pk2(a.z, a.w);
  o.z = pk2(b.x, b.y); o.w = pk2(b.z, b.w);
  *(uint4*)(out + i) = o;
}

// ---------------------------------------------------------------------------
// Transpose + convert: W fp32 [k][n] (1024x1024) -> Wt bf16 [n][k]
// ---------------------------------------------------------------------------
__global__ __launch_bounds__(256)
void wtrans(const float* __restrict__ W, u16* __restrict__ Wt)
{
  __shared__ __align__(16) u16 T[64][68];
  const int k0 = blockIdx.y * 64, n0 = blockIdx.x * 64;
  const int t = threadIdx.x;
  #pragma unroll
  for (int p = 0; p < 16; ++p){
    int e = p*256 + t, k = e >> 6, n = e & 63;
    T[n][k] = f2b(W[(size_t)(k0+k)*DM + n0 + n]);
  }
  __syncthreads();
  #pragma unroll
  for (int p = 0; p < 8; ++p){
    int e = p*256 + t, n = e >> 5, kp = e & 31;
    u32 val = *(const u32*)&T[n][2*kp];
    *(u32*)&Wt[(size_t)(n0+n)*DM + k0 + 2*kp] = val;
  }
}

// ---------------------------------------------------------------------------
// m97-structure MFMA GEMM: C[m][n] = (sum_k A[m][k]*Wt[n][k] + bias[n]) * X
// A bf16 [M][1024], Wt bf16 [N][1024]. 128x128 tile, BK=32, 256 thr
// (4 waves, 2x2 of 64x64). global_load_lds 16B staging, unpadded LDS.
// OMODE: 0 = bf16 C[m][DM] * cmul
//        1 = bf16 Vt[((b*NH+h)*DK+d)*SEQ + s] * Linv[bh][s]
//        2 = fp32 C[m][DM]
// ---------------------------------------------------------------------------
template<int OMODE>
__global__ __launch_bounds__(256)
void gemm_m97(const u16* __restrict__ A, const u16* __restrict__ Wt,
              const float* __restrict__ bias, const float* __restrict__ Linv,
              void* __restrict__ Cp, float cmul)
{
  __shared__ __align__(16) u16 Asm[128*32];   // [row][32k], 64B rows, no pad
  __shared__ __align__(16) u16 Bsm[128*32];
  const int bm = blockIdx.y * 128, bn = blockIdx.x * 128;
  const int t = threadIdx.x, wid = t >> 6, l = t & 63, r16 = l & 15, q = l >> 4;
  const int wm = (wid & 1) * 64, wn = (wid >> 1) * 64;
  // staging: lds linear = s*4096B + wid*1024B + lane*16B
  //   row = s*64 + wid*16 + l/4 ; k16 = (l&3)*8
  const int rL = wid*16 + (l >> 2), kL = (l & 3) * 8;
  const u16* Ag = A  + (size_t)(bm + rL)*DM + kL;
  const u16* Bg = Wt + (size_t)(bn + rL)*DM + kL;
  u16* AsmW = Asm + wid*512;   // u16 units (1KB per wave)
  u16* BsmW = Bsm + wid*512;
  floatx4 acc[4][4] = {};

  for (int kc = 0; kc < DM; kc += 32){
    gld_lds16(Ag + kc,                AsmW);
    gld_lds16(Ag + kc + (size_t)64*DM, AsmW + 2048);
    gld_lds16(Bg + kc,                BsmW);
    gld_lds16(Bg + kc + (size_t)64*DM, BsmW + 2048);
    __syncthreads();              // drains vmcnt -> tiles ready
    bhalf8 af[4], bf[4];
    #pragma unroll
    for (int i = 0; i < 4; ++i) af[i] = *(const bhalf8*)&Asm[(wm + i*16 + r16)*32 + q*8];
    #pragma unroll
    for (int j = 0; j < 4; ++j) bf[j] = *(const bhalf8*)&Bsm[(wn + j*16 + r16)*32 + q*8];
    #pragma unroll
    for (int i = 0; i < 4; ++i)
      #pragma unroll
      for (int j = 0; j < 4; ++j)
        acc[i][j] = MFMA16(af[i], bf[j], acc[i][j]);
    __syncthreads();              // frag reads done before next overwrite
  }

  // epilogue: D row = wm+i*16+q*4+r, col = wn+j*16+r16
  if (OMODE == 0){
    u16* C = (u16*)Cp;
    #pragma unroll
    for (int j = 0; j < 4; ++j){
      const int n = bn + wn + j*16 + r16;
      const float bj = bias[n];
      #pragma unroll
      for (int i = 0; i < 4; ++i){
        const int m0 = bm + wm + i*16 + q*4;
        #pragma unroll
        for (int r = 0; r < 4; ++r)
          C[(size_t)(m0+r)*DM + n] = f2b((acc[i][j][r] + bj) * cmul);
      }
    }
  } else if (OMODE == 1){
    u16* C = (u16*)Cp;
    const int h  = (bn + wn) >> 6;           // wn is 64-aligned: one head/wave
    const int bb = (bm + wm) >> 11;
    const int s0 = (bm + wm) & (SEQ - 1);
    #pragma unroll
    for (int i = 0; i < 4; ++i){
      const int sl = s0 + i*16 + q*4;
      const float4 sc = *(const float4*)(Linv + (size_t)(bb*NH + h)*SEQ + sl);
      #pragma unroll
      for (int j = 0; j < 4; ++j){
        const int d = j*16 + r16;
        const float bj = bias[h*DK + d];
        u32 v0 = pk2((acc[i][j][0]+bj)*sc.x, (acc[i][j][1]+bj)*sc.y);
        u32 v1 = pk2((acc[i][j][2]+bj)*sc.z, (acc[i][j][3]+bj)*sc.w);
        *(uint2*)&C[((size_t)(bb*NH + h)*DK + d)*SEQ + sl] = make_uint2(v0, v1);
      }
    }
  } else {
    float* C = (float*)Cp;
    #pragma unroll
    for (int j = 0; j < 4; ++j){
      const int n = bn + wn + j*16 + r16;
      const float bj = bias[n];
      #pragma unroll
      for (int i = 0; i < 4; ++i){
        const int m0 = bm + wm + i*16 + q*4;
        #pragma unroll
        for (int r = 0; r < 4; ++r)
          C[(size_t)(m0+r)*DM + n] = acc[i][j][r] + bj;
      }
    }
  }
}

// ---------------------------------------------------------------------------
// Stats: Linv[bh][j] = 1 / sum_i 2^(s'_ij).  (no max needed; |s'| small)
// Block = (64-wide j tile, bh). K-frags in regs, Q-frags direct global.
// ---------------------------------------------------------------------------
__global__ __launch_bounds__(256)
void attn_stats(const u16* __restrict__ Qb, const u16* __restrict__ Kb,
                float* __restrict__ Linv)
{
  __shared__ float pl[4][64];
  const int j0 = blockIdx.x * 64, bh = blockIdx.y, b = bh >> 4, h = bh & 15;
  const int t = threadIdx.x, wid = t >> 6, l = t & 63, r16 = l & 15, q = l >> 4;

  bhalf8 kf[4][2];
  const u16* kp = Kb + (size_t)(b*SEQ + j0 + r16)*DM + h*DK + q*8;
  #pragma unroll
  for (int st = 0; st < 4; ++st){
    kf[st][0] = *(const bhalf8*)(kp + (size_t)st*16*DM);
    kf[st][1] = *(const bhalf8*)(kp + (size_t)st*16*DM + 32);
  }
  float rl[4] = {0.f, 0.f, 0.f, 0.f};
  const u16* qp = Qb + (size_t)(b*SEQ + wid*16 + r16)*DM + h*DK + q*8;
  for (int it = 0; it < SEQ/64; ++it){
    bhalf8 qf0 = *(const bhalf8*)qp;
    bhalf8 qf1 = *(const bhalf8*)(qp + 32);
    qp += (size_t)64*DM;
    #pragma unroll
    for (int st = 0; st < 4; ++st){
      floatx4 s = {};
      s = MFMA16(qf0, kf[st][0], s);
      s = MFMA16(qf1, kf[st][1], s);
      rl[st] += exp2f(s[0]) + exp2f(s[1]) + exp2f(s[2]) + exp2f(s[3]);
    }
  }
  #pragma unroll
  for (int st = 0; st < 4; ++st){
    float v = rl[st];
    v += __shfl_xor(v, 16);
    v += __shfl_xor(v, 32);
    rl[st] = v;
  }
  if (q == 0){
    #pragma unroll
    for (int st = 0; st < 4; ++st) pl[wid][st*16 + r16] = rl[st];
  }
  __syncthreads();
  if (t < 64)
    Linv[(size_t)bh*SEQ + j0 + t] = 1.f / (pl[0][t] + pl[1][t] + pl[2][t] + pl[3][t]);
}

// ---------------------------------------------------------------------------
// PV: X[i][d] = sum_j 2^(s'_ij) * V'[j][d]   (V' pre-scaled by Linv)
// i-tile 128 (wave owns 32 rows as 2 frag groups), j-tile 64.
// S^T trick: MFMA(K,Q) -> D[j][i] -> b64 P-writes. K/V dbuf LDS; 2 barriers/jt.
// ---------------------------------------------------------------------------
__global__ __launch_bounds__(256)
void attn_pv(const u16* __restrict__ Qb, const u16* __restrict__ Kb,
             const u16* __restrict__ Vt, u16* __restrict__ Xb)
{
  __shared__ __align__(16) u16 Kls[2][64][72];
  __shared__ __align__(16) u16 Vls[2][64][72];
  __shared__ __align__(16) u16 Pls[128][72];
  const int i0 = blockIdx.x * 128, bh = blockIdx.y, b = bh >> 4, h = bh & 15;
  const int t = threadIdx.x, wid = t >> 6, l = t & 63, r16 = l & 15, q = l >> 4;
  const int sr = t >> 2, sc = t & 3;

  // Q fragments: wave's 32 i-rows, 2 groups of 16
  bhalf8 qf[2][2];
  #pragma unroll
  for (int g = 0; g < 2; ++g){
    const u16* qp = Qb + (size_t)(b*SEQ + i0 + wid*32 + g*16 + r16)*DM + h*DK + q*8;
    qf[g][0] = *(const bhalf8*)qp;
    qf[g][1] = *(const bhalf8*)(qp + 32);
  }

  const u16* krow = Kb + (size_t)(b*SEQ + sr)*DM + h*DK;   // + jt*64*DM per tile
  const u16* vrow = Vt + ((size_t)bh*DK + sr)*SEQ;         // + jt*64 per tile
  {
    *(uint4*)&Kls[0][sr][sc*8]      = *(const uint4*)(krow + sc*8);
    *(uint4*)&Kls[0][sr][sc*8 + 32] = *(const uint4*)(krow + sc*8 + 32);
    *(uint4*)&Vls[0][sr][sc*8]      = *(const uint4*)(vrow + sc*8);
    *(uint4*)&Vls[0][sr][sc*8 + 32] = *(const uint4*)(vrow + sc*8 + 32);
  }
  __syncthreads();

  floatx4 xacc[2][4] = {};
  for (int jt = 0; jt < SEQ/64; ++jt){
    const int p = jt & 1;
    // stage next tile into other buffer (clamped dup on last iter is harmless)
    const int jn = (jt + 1 < SEQ/64) ? (jt + 1) : (SEQ/64 - 1);
    {
      const u16* ks = krow + (size_t)jn*64*DM;
      const u16* vs = vrow + jn*64;
      *(uint4*)&Kls[p^1][sr][sc*8]      = *(const uint4*)(ks + sc*8);
      *(uint4*)&Kls[p^1][sr][sc*8 + 32] = *(const uint4*)(ks + sc*8 + 32);
      *(uint4*)&Vls[p^1][sr][sc*8]      = *(const uint4*)(vs + sc*8);
      *(uint4*)&Vls[p^1][sr][sc*8 + 32] = *(const uint4*)(vs + sc*8 + 32);
    }
    // S^T: A=K (j rows), B=Q (i cols). P = 2^s' -> Pls[i][j]
    #pragma unroll
    for (int st = 0; st < 4; ++st){
      bhalf8 k0 = *(const bhalf8*)&Kls[p][st*16 + r16][q*8];
      bhalf8 k1 = *(const bhalf8*)&Kls[p][st*16 + r16][32 + q*8];
      #pragma unroll
      for (int g = 0; g < 2; ++g){
        floatx4 s = {};
        s = MFMA16(k0, qf[g][0], s);
        s = MFMA16(k1, qf[g][1], s);
        u32 lo = pk2(exp2f(s[0]), exp2f(s[1]));
        u32 hi = pk2(exp2f(s[2]), exp2f(s[3]));
        *(uint2*)&Pls[wid*32 + g*16 + r16][st*16 + q*4] = make_uint2(lo, hi);
      }
    }
    __syncthreads();   // P visible (staging writes also drained)
    #pragma unroll
    for (int g = 0; g < 2; ++g){
      bhalf8 pf0 = *(const bhalf8*)&Pls[wid*32 + g*16 + r16][q*8];
      bhalf8 pf1 = *(const bhalf8*)&Pls[wid*32 + g*16 + r16][32 + q*8];
      #pragma unroll
      for (int dst = 0; dst < 4; ++dst){
        bhalf8 v0 = *(const bhalf8*)&Vls[p][dst*16 + r16][q*8];
        bhalf8 v1 = *(const bhalf8*)&Vls[p][dst*16 + r16][32 + q*8];
        xacc[g][dst] = MFMA16(pf0, v0, xacc[g][dst]);
        xacc[g][dst] = MFMA16(pf1, v1, xacc[g][dst]);
      }
    }
    __syncthreads();   // P reads done; next iter may overwrite Pls
  }

  #pragma unroll
  for (int g = 0; g < 2; ++g)
    #pragma unroll
    for (int dst = 0; dst < 4; ++dst)
      #pragma unroll
      for (int r = 0; r < 4; ++r)
        Xb[(size_t)(b*SEQ + i0 + wid*32 + g*16 + q*4 + r)*DM + h*DK + dst*16 + r16]
          = f2b(xacc[g][dst][r]);
}

// ---------------------------------------------------------------------------
extern "C" void kernel_launch(void* const* d_in, const int* in_sizes, int n_in,
                              void* d_out, int out_size, void* d_ws, size_t ws_size,
                              hipStream_t stream)
{
  const float* q  = (const float*)d_in[0];
  const float* k  = (const float*)d_in[1];
  const float* v  = (const float*)d_in[2];
  const float* Wq = (const float*)d_in[3];
  const float* bq = (const float*)d_in[4];
  const float* Wk = (const float*)d_in[5];
  const float* bk = (const float*)d_in[6];
  const float* Wv = (const float*)d_in[7];
  const float* bv = (const float*)d_in[8];
  const float* Wo = (const float*)d_in[9];
  const float* bo = (const float*)d_in[10];
  float* out = (float*)d_out;

  // ws: [Linv 256K][Wt 2M shared][AbXb 8M shared][Qb 8M][Kb 8M][Vt 8M] = 34.25 MiB
  char* ws = (char*)d_ws;
  const size_t STATB = (size_t)NH * 2 * SEQ * sizeof(float);   // 256 KiB
  const size_t WTB   = (size_t)DM * DM * sizeof(u16);          // 2 MiB
  const size_t TOKB  = (size_t)NTOK * DM * sizeof(u16);        // 8 MiB
  float* Linv = (float*)(ws);
  u16*   Wt   = (u16*)(ws + STATB);
  u16*   Ab   = (u16*)(ws + STATB + WTB);        // conv scratch, later Xb
  u16*   Xb   = Ab;
  u16*   Qb   = (u16*)(ws + STATB + WTB + TOKB);
  u16*   Kb   = (u16*)(ws + STATB + WTB + 2*TOKB);
  u16*   Vt   = (u16*)(ws + STATB + WTB + 3*TOKB);

  dim3 blk(256);
  dim3 gc((NTOK*DM)/(256*8));     // 2048 blocks
  dim3 gt(16, 16);
  dim3 gg(DM/128, NTOK/128);      // (8, 32)
  dim3 ga(SEQ/64,  NH*2);         // (32, 32)
  dim3 gp(SEQ/128, NH*2);         // (16, 32)

  // Q projection (pre-scaled by 0.125*log2 e)
  cvt_bf16<<<gc, blk, 0, stream>>>(q, Ab);
  wtrans<<<gt, blk, 0, stream>>>(Wq, Wt);
  gemm_m97<0><<<gg, blk, 0, stream>>>(Ab, Wt, bq, nullptr, Qb, C1);
  // K projection
  cvt_bf16<<<gc, blk, 0, stream>>>(k, Ab);
  wtrans<<<gt, blk, 0, stream>>>(Wk, Wt);
  gemm_m97<0><<<gg, blk, 0, stream>>>(Ab, Wt, bk, nullptr, Kb, 1.0f);
  // softmax-over-i denominators
  attn_stats<<<ga, blk, 0, stream>>>(Qb, Kb, Linv);
  // V projection: transposed output, Linv folded in
  cvt_bf16<<<gc, blk, 0, stream>>>(v, Ab);
  wtrans<<<gt, blk, 0, stream>>>(Wv, Wt);
  gemm_m97<1><<<gg, blk, 0, stream>>>(Ab, Wt, bv, Linv, Vt, 1.0f);
  // attention (Ab no longer needed -> reused as Xb)
  attn_pv<<<gp, blk, 0, stream>>>(Qb, Kb, Vt, Xb);
  // output projection
  wtrans<<<gt, blk, 0, stream>>>(Wo, Wt);
  gemm_m97<2><<<gg, blk, 0, stream>>>(Xb, Wt, bo, nullptr, out, 1.0f);
}

// Round 7
// 289.516 us; speedup vs baseline: 1.6930x; 1.2186x over previous
//
#include <hip/hip_runtime.h>
#include <hip/hip_bf16.h>

#define SEQ   2048
#define NH    16
#define DK    64
#define DM    1024
#define NTOK  4096
#define C1    0.1803368801111204f   // 0.125 * log2(e)

typedef unsigned short u16;
typedef unsigned int   u32;
typedef short bhalf8 __attribute__((ext_vector_type(8)));   // 8 bf16 = 4 VGPRs
typedef float floatx4 __attribute__((ext_vector_type(4)));  // MFMA acc

#define MFMA16(a,b,c) __builtin_amdgcn_mfma_f32_16x16x32_bf16(a,b,c,0,0,0)

#if __has_builtin(__builtin_amdgcn_exp2f)
#define EXP2(x) __builtin_amdgcn_exp2f(x)
#else
#define EXP2(x) exp2f(x)
#endif

__device__ __forceinline__ u16 f2b(float f){
  union { float f; u32 u; } v; v.f = f;
  u32 r = v.u + 0x7fffu + ((v.u >> 16) & 1u);
  return (u16)(r >> 16);
}
__device__ __forceinline__ u32 pk2(float a, float b){
  union { __hip_bfloat162 h; u32 w; } o;
  o.h = __float22bfloat162_rn(make_float2(a, b));
  return o.w;
}
// async global->LDS, 16B/lane; lds ptr must be wave-uniform (HW adds lane*16)
__device__ __forceinline__ void gld_lds16(const u16* g, u16* lds){
  __builtin_amdgcn_global_load_lds(
      (const __attribute__((address_space(1))) u32*)g,
      (__attribute__((address_space(3))) u32*)lds, 16, 0, 0);
}

// ---------------------------------------------------------------------------
// Fused fp32->bf16 convert for q,k,v (memory-bound), 8 elems/thread
// ---------------------------------------------------------------------------
__global__ __launch_bounds__(256)
void cvt_qkv(const float* __restrict__ q, const float* __restrict__ k,
             const float* __restrict__ v, u16* __restrict__ Aq,
             u16* __restrict__ Ak, u16* __restrict__ Av)
{
  const float* in = (blockIdx.y == 0) ? q : (blockIdx.y == 1) ? k : v;
  u16* out       = (blockIdx.y == 0) ? Aq : (blockIdx.y == 1) ? Ak : Av;
  const size_t i = ((size_t)blockIdx.x * 256 + threadIdx.x) * 8;
  const float4 a = *(const float4*)(in + i);
  const float4 b = *(const float4*)(in + i + 4);
  uint4 o;
  o.x = pk2(a.x, a.y); o.y = pk2(a.z, a.w);
  o.z = pk2(b.x, b.y); o.w = pk2(b.z, b.w);
  *(uint4*)(out + i) = o;
}

// ---------------------------------------------------------------------------
// Fused transpose+convert: 4 weights fp32 [k][n] -> Wtall bf16 [z][n][k]
// ---------------------------------------------------------------------------
__global__ __launch_bounds__(256)
void wtrans4(const float* __restrict__ Wq, const float* __restrict__ Wk,
             const float* __restrict__ Wv, const float* __restrict__ Wo,
             u16* __restrict__ Wtall)
{
  __shared__ __align__(16) u16 T[64][68];
  const int z = blockIdx.z;
  const float* W = (z == 0) ? Wq : (z == 1) ? Wk : (z == 2) ? Wv : Wo;
  u16* Wt = Wtall + (size_t)z * DM * DM;
  const int k0 = blockIdx.y * 64, n0 = blockIdx.x * 64;
  const int t = threadIdx.x;
  #pragma unroll
  for (int p = 0; p < 16; ++p){
    int e = p*256 + t, k = e >> 6, n = e & 63;
    T[n][k] = f2b(W[(size_t)(k0+k)*DM + n0 + n]);
  }
  __syncthreads();
  #pragma unroll
  for (int p = 0; p < 8; ++p){
    int e = p*256 + t, n = e >> 5, kp = e & 31;
    u32 val = *(const u32*)&T[n][2*kp];
    *(u32*)&Wt[(size_t)(n0+n)*DM + k0 + 2*kp] = val;
  }
}

// ---------------------------------------------------------------------------
// Fused Q/K/V projection GEMM (m97 structure + XOR-swizzled LDS).
// grid (DM/128, NTOK/128, 3); z picks A/W/bias/output.
// z=0: Qb = (q W + b)*C1 ; z=1: Kb ; z=2: Vt[((b*NH+h)*DK+d)*SEQ+s] (no scale)
// ---------------------------------------------------------------------------
__global__ __launch_bounds__(256)
void gemm_qkv(const u16* __restrict__ Aq, const u16* __restrict__ Ak,
              const u16* __restrict__ Av, const u16* __restrict__ Wtall,
              const float* __restrict__ bq, const float* __restrict__ bk,
              const float* __restrict__ bv, u16* __restrict__ Qb,
              u16* __restrict__ Kb, u16* __restrict__ Vt)
{
  __shared__ __align__(16) u16 Asm[128*32];   // rows of 64B (4 chunks), swizzled
  __shared__ __align__(16) u16 Bsm[128*32];
  const int z = blockIdx.z;
  const u16* A = (z == 0) ? Aq : (z == 1) ? Ak : Av;
  const u16* Wt = Wtall + (size_t)z * DM * DM;
  const float* bias = (z == 0) ? bq : (z == 1) ? bk : bv;
  const float cmul = (z == 0) ? C1 : 1.0f;

  const int bm = blockIdx.y * 128, bn = blockIdx.x * 128;
  const int t = threadIdx.x, wid = t >> 6, l = t & 63, r16 = l & 15, q = l >> 4;
  const int wm = (wid & 1) * 64, wn = (wid >> 1) * 64;
  // staging: lds slot = t (16B units); row = t>>2, slot-chunk = t&3,
  // global chunk g = (t&3) ^ (row&3)  (XOR swizzle)
  const int rL = t >> 2, gL = ((t & 3) ^ (rL & 3)) * 8;
  const u16* Ag = A  + (size_t)(bm + rL)*DM + gL;
  const u16* Bg = Wt + (size_t)(bn + rL)*DM + gL;
  u16* AsmW = Asm + wid*512;
  u16* BsmW = Bsm + wid*512;
  const int sw = (r16 & 3);   // frag-read swizzle key
  floatx4 acc[4][4] = {};

  for (int kc = 0; kc < DM; kc += 32){
    gld_lds16(Ag + kc,                 AsmW);
    gld_lds16(Ag + kc + (size_t)64*DM, AsmW + 2048);
    gld_lds16(Bg + kc,                 BsmW);
    gld_lds16(Bg + kc + (size_t)64*DM, BsmW + 2048);
    __syncthreads();
    bhalf8 af[4], bf[4];
    #pragma unroll
    for (int i = 0; i < 4; ++i)
      af[i] = *(const bhalf8*)&Asm[(wm + i*16 + r16)*32 + ((q ^ sw)*8)];
    #pragma unroll
    for (int j = 0; j < 4; ++j)
      bf[j] = *(const bhalf8*)&Bsm[(wn + j*16 + r16)*32 + ((q ^ sw)*8)];
    #pragma unroll
    for (int i = 0; i < 4; ++i)
      #pragma unroll
      for (int j = 0; j < 4; ++j)
        acc[i][j] = MFMA16(af[i], bf[j], acc[i][j]);
    __syncthreads();
  }

  if (z < 2){
    u16* C = (z == 0) ? Qb : Kb;
    #pragma unroll
    for (int j = 0; j < 4; ++j){
      const int n = bn + wn + j*16 + r16;
      const float bj = bias[n];
      #pragma unroll
      for (int i = 0; i < 4; ++i){
        const int m0 = bm + wm + i*16 + q*4;
        #pragma unroll
        for (int r = 0; r < 4; ++r)
          C[(size_t)(m0+r)*DM + n] = f2b((acc[i][j][r] + bj) * cmul);
      }
    }
  } else {
    const int h  = (bn + wn) >> 6;
    const int bb = (bm + wm) >> 11;
    const int s0 = (bm + wm) & (SEQ - 1);
    #pragma unroll
    for (int i = 0; i < 4; ++i){
      const int sl = s0 + i*16 + q*4;
      #pragma unroll
      for (int j = 0; j < 4; ++j){
        const int d = j*16 + r16;
        const float bj = bias[h*DK + d];
        u32 v0 = pk2(acc[i][j][0]+bj, acc[i][j][1]+bj);
        u32 v1 = pk2(acc[i][j][2]+bj, acc[i][j][3]+bj);
        *(uint2*)&Vt[((size_t)(bb*NH + h)*DK + d)*SEQ + sl] = make_uint2(v0, v1);
      }
    }
  }
}

// ---------------------------------------------------------------------------
// O-projection GEMM (same structure), A bf16 -> out fp32
// ---------------------------------------------------------------------------
__global__ __launch_bounds__(256)
void gemm_o(const u16* __restrict__ A, const u16* __restrict__ Wt,
            const float* __restrict__ bias, float* __restrict__ C)
{
  __shared__ __align__(16) u16 Asm[128*32];
  __shared__ __align__(16) u16 Bsm[128*32];
  const int bm = blockIdx.y * 128, bn = blockIdx.x * 128;
  const int t = threadIdx.x, wid = t >> 6, l = t & 63, r16 = l & 15, q = l >> 4;
  const int wm = (wid & 1) * 64, wn = (wid >> 1) * 64;
  const int rL = t >> 2, gL = ((t & 3) ^ (rL & 3)) * 8;
  const u16* Ag = A  + (size_t)(bm + rL)*DM + gL;
  const u16* Bg = Wt + (size_t)(bn + rL)*DM + gL;
  u16* AsmW = Asm + wid*512;
  u16* BsmW = Bsm + wid*512;
  const int sw = (r16 & 3);
  floatx4 acc[4][4] = {};

  for (int kc = 0; kc < DM; kc += 32){
    gld_lds16(Ag + kc,                 AsmW);
    gld_lds16(Ag + kc + (size_t)64*DM, AsmW + 2048);
    gld_lds16(Bg + kc,                 BsmW);
    gld_lds16(Bg + kc + (size_t)64*DM, BsmW + 2048);
    __syncthreads();
    bhalf8 af[4], bf[4];
    #pragma unroll
    for (int i = 0; i < 4; ++i)
      af[i] = *(const bhalf8*)&Asm[(wm + i*16 + r16)*32 + ((q ^ sw)*8)];
    #pragma unroll
    for (int j = 0; j < 4; ++j)
      bf[j] = *(const bhalf8*)&Bsm[(wn + j*16 + r16)*32 + ((q ^ sw)*8)];
    #pragma unroll
    for (int i = 0; i < 4; ++i)
      #pragma unroll
      for (int j = 0; j < 4; ++j)
        acc[i][j] = MFMA16(af[i], bf[j], acc[i][j]);
    __syncthreads();
  }
  #pragma unroll
  for (int j = 0; j < 4; ++j){
    const int n = bn + wn + j*16 + r16;
    const float bj = bias[n];
    #pragma unroll
    for (int i = 0; i < 4; ++i){
      const int m0 = bm + wm + i*16 + q*4;
      #pragma unroll
      for (int r = 0; r < 4; ++r)
        C[(size_t)(m0+r)*DM + n] = acc[i][j][r] + bj;
    }
  }
}

// ---------------------------------------------------------------------------
// Stats + fold: compute l_j = sum_i 2^(s'_ij) for its 64 j's, then scale
// Vt[bh][d][j] *= 1/l_j in place. Linv never touches global.
// ---------------------------------------------------------------------------
__global__ __launch_bounds__(256)
void attn_stats(const u16* __restrict__ Qb, const u16* __restrict__ Kb,
                u16* __restrict__ Vt)
{
  __shared__ float pl[4][64];
  __shared__ float sLinv[64];
  const int j0 = blockIdx.x * 64, bh = blockIdx.y, b = bh >> 4, h = bh & 15;
  const int t = threadIdx.x, wid = t >> 6, l = t & 63, r16 = l & 15, q = l >> 4;

  bhalf8 kf[4][2];
  const u16* kp = Kb + (size_t)(b*SEQ + j0 + r16)*DM + h*DK + q*8;
  #pragma unroll
  for (int st = 0; st < 4; ++st){
    kf[st][0] = *(const bhalf8*)(kp + (size_t)st*16*DM);
    kf[st][1] = *(const bhalf8*)(kp + (size_t)st*16*DM + 32);
  }
  float rl[4] = {0.f, 0.f, 0.f, 0.f};
  const u16* qp = Qb + (size_t)(b*SEQ + wid*16 + r16)*DM + h*DK + q*8;
  for (int it = 0; it < SEQ/64; ++it){
    bhalf8 qf0 = *(const bhalf8*)qp;
    bhalf8 qf1 = *(const bhalf8*)(qp + 32);
    qp += (size_t)64*DM;
    #pragma unroll
    for (int st = 0; st < 4; ++st){
      floatx4 s = {};
      s = MFMA16(qf0, kf[st][0], s);
      s = MFMA16(qf1, kf[st][1], s);
      rl[st] += EXP2(s[0]) + EXP2(s[1]) + EXP2(s[2]) + EXP2(s[3]);
    }
  }
  #pragma unroll
  for (int st = 0; st < 4; ++st){
    float v = rl[st];
    v += __shfl_xor(v, 16);
    v += __shfl_xor(v, 32);
    rl[st] = v;
  }
  if (q == 0){
    #pragma unroll
    for (int st = 0; st < 4; ++st) pl[wid][st*16 + r16] = rl[st];
  }
  __syncthreads();
  if (t < 64)
    sLinv[t] = 1.f / (pl[0][t] + pl[1][t] + pl[2][t] + pl[3][t]);
  __syncthreads();
  // scale Vt[bh][d][j0..j0+63] by sLinv[j-j0]; 16 elems/thread
  {
    const int d = t >> 2, cb = (t & 3) * 16;
    u16* vp = Vt + ((size_t)bh*DK + d)*SEQ + j0 + cb;
    uint4 w0 = *(uint4*)vp, w1 = *(uint4*)(vp + 8);
    float sc[16];
    #pragma unroll
    for (int e = 0; e < 16; ++e) sc[e] = sLinv[cb + e];
    #define SC2(w, s0, s1) pk2(__uint_as_float((w) << 16) * (s0), \
                               __uint_as_float((w) & 0xffff0000u) * (s1))
    w0.x = SC2(w0.x, sc[0],  sc[1]);  w0.y = SC2(w0.y, sc[2],  sc[3]);
    w0.z = SC2(w0.z, sc[4],  sc[5]);  w0.w = SC2(w0.w, sc[6],  sc[7]);
    w1.x = SC2(w1.x, sc[8],  sc[9]);  w1.y = SC2(w1.y, sc[10], sc[11]);
    w1.z = SC2(w1.z, sc[12], sc[13]); w1.w = SC2(w1.w, sc[14], sc[15]);
    #undef SC2
    *(uint4*)vp = w0; *(uint4*)(vp + 8) = w1;
  }
}

// ---------------------------------------------------------------------------
// PV: X[i][d] = sum_j 2^(s'_ij) * V'[j][d]  (V' pre-scaled by 1/l_j)
// i-tile 128 (wave = 32 i as 2 groups). K/V staged via global_load_lds with
// 16B-chunk XOR swizzle (single buffer, 2 barriers/jt). P per-wave in LDS.
// ---------------------------------------------------------------------------
__global__ __launch_bounds__(256)
void attn_pv(const u16* __restrict__ Qb, const u16* __restrict__ Kb,
             const u16* __restrict__ Vt, u16* __restrict__ Xb)
{
  __shared__ __align__(16) u16 Kls[64*64];       // [j][d], 128B rows, swizzled
  __shared__ __align__(16) u16 Vls[64*64];       // [d][s], 128B rows, swizzled
  __shared__ __align__(16) u16 Pls[4][32][72];   // per-wave P[i][j], padded
  const int i0 = blockIdx.x * 128, bh = blockIdx.y, b = bh >> 4, h = bh & 15;
  const int t = threadIdx.x, wid = t >> 6, l = t & 63, r16 = l & 15, q = l >> 4;

  // Q fragments: wave's 32 i-rows as 2 groups of 16 (direct global)
  bhalf8 qf[2][2];
  #pragma unroll
  for (int g = 0; g < 2; ++g){
    const u16* qp = Qb + (size_t)(b*SEQ + i0 + wid*32 + g*16 + r16)*DM + h*DK + q*8;
    qf[g][0] = *(const bhalf8*)qp;
    qf[g][1] = *(const bhalf8*)(qp + 32);
  }

  // gld staging: slot = call*256 + t; row = slot>>3, chunk c = slot&7,
  // global chunk g = c ^ (row&7)
  const int row0 = t >> 3, c0 = t & 7;
  const int g0 = (c0 ^ (row0 & 7)) * 8;
  const int row1 = row0 + 32;
  const int g1 = (c0 ^ (row1 & 7)) * 8;
  const u16* kp0 = Kb + (size_t)(b*SEQ + row0)*DM + h*DK + g0;
  const u16* kp1 = Kb + (size_t)(b*SEQ + row1)*DM + h*DK + g1;
  const u16* vp0 = Vt + ((size_t)bh*DK + row0)*SEQ + g0;
  const u16* vp1 = Vt + ((size_t)bh*DK + row1)*SEQ + g1;
  u16* kdst = Kls + wid*512;
  u16* vdst = Vls + wid*512;
  const int sw = (r16 & 7);   // frag-read swizzle key

  floatx4 xacc[2][4] = {};
  for (int jt = 0; jt < SEQ/64; ++jt){
    gld_lds16(kp0 + (size_t)jt*64*DM, kdst);
    gld_lds16(kp1 + (size_t)jt*64*DM, kdst + 2048);
    gld_lds16(vp0 + jt*64,            vdst);
    gld_lds16(vp1 + jt*64,            vdst + 2048);
    __syncthreads();                 // vmcnt drained: tiles ready

    // S^T: A=K (j rows), B=Q (i cols) -> D[j][i]; P = 2^s' -> Pls[i][j]
    #pragma unroll
    for (int st = 0; st < 4; ++st){
      const int kr = (st*16 + r16) * 64;
      bhalf8 k0 = *(const bhalf8*)&Kls[kr + ((q     ^ sw) * 8)];
      bhalf8 k1 = *(const bhalf8*)&Kls[kr + (((q+4) ^ sw) * 8)];
      #pragma unroll
      for (int g = 0; g < 2; ++g){
        floatx4 s = {};
        s = MFMA16(k0, qf[g][0], s);
        s = MFMA16(k1, qf[g][1], s);
        u32 lo = pk2(EXP2(s[0]), EXP2(s[1]));
        u32 hi = pk2(EXP2(s[2]), EXP2(s[3]));
        *(uint2*)&Pls[wid][g*16 + r16][st*16 + q*4] = make_uint2(lo, hi);
      }
    }
    // P round-trip is wave-local: lgkmcnt ordering only, no barrier
    #pragma unroll
    for (int g = 0; g < 2; ++g){
      bhalf8 pf0 = *(const bhalf8*)&Pls[wid][g*16 + r16][q*8];
      bhalf8 pf1 = *(const bhalf8*)&Pls[wid][g*16 + r16][32 + q*8];
      #pragma unroll
      for (int dst = 0; dst < 4; ++dst){
        const int vr = (dst*16 + r16) * 64;
        bhalf8 v0 = *(const bhalf8*)&Vls[vr + ((q     ^ sw) * 8)];
        bhalf8 v1 = *(const bhalf8*)&Vls[vr + (((q+4) ^ sw) * 8)];
        xacc[g][dst] = MFMA16(pf0, v0, xacc[g][dst]);
        xacc[g][dst] = MFMA16(pf1, v1, xacc[g][dst]);
      }
    }
    __syncthreads();                 // all frag reads done before next gld
  }

  #pragma unroll
  for (int g = 0; g < 2; ++g)
    #pragma unroll
    for (int dst = 0; dst < 4; ++dst)
      #pragma unroll
      for (int r = 0; r < 4; ++r)
        Xb[(size_t)(b*SEQ + i0 + wid*32 + g*16 + q*4 + r)*DM + h*DK + dst*16 + r16]
          = f2b(xacc[g][dst][r]);
}

// ---------------------------------------------------------------------------
extern "C" void kernel_launch(void* const* d_in, const int* in_sizes, int n_in,
                              void* d_out, int out_size, void* d_ws, size_t ws_size,
                              hipStream_t stream)
{
  const float* q  = (const float*)d_in[0];
  const float* k  = (const float*)d_in[1];
  const float* v  = (const float*)d_in[2];
  const float* Wq = (const float*)d_in[3];
  const float* bq = (const float*)d_in[4];
  const float* Wk = (const float*)d_in[5];
  const float* bk = (const float*)d_in[6];
  const float* Wv = (const float*)d_in[7];
  const float* bv = (const float*)d_in[8];
  const float* Wo = (const float*)d_in[9];
  const float* bo = (const float*)d_in[10];
  float* out = (float*)d_out;

  // ws: [Wtall 8M][Aq 8M (=Xb)][Ak 8M][Av 8M][Qb 8M][Kb 8M][Vt 8M] = 56 MiB
  char* ws = (char*)d_ws;
  const size_t WTB  = (size_t)DM * DM * sizeof(u16);    // 2 MiB
  const size_t TOKB = (size_t)NTOK * DM * sizeof(u16);  // 8 MiB
  u16* Wtall = (u16*)(ws);
  u16* Aq    = (u16*)(ws + 4*WTB);
  u16* Ak    = (u16*)(ws + 4*WTB + TOKB);
  u16* Av    = (u16*)(ws + 4*WTB + 2*TOKB);
  u16* Qb    = (u16*)(ws + 4*WTB + 3*TOKB);
  u16* Kb    = (u16*)(ws + 4*WTB + 4*TOKB);
  u16* Vt    = (u16*)(ws + 4*WTB + 5*TOKB);
  u16* Xb    = Aq;   // Aq consumed by gemm_qkv before pv writes Xb

  dim3 blk(256);
  cvt_qkv<<<dim3((NTOK*DM)/(256*8), 3), blk, 0, stream>>>(q, k, v, Aq, Ak, Av);
  wtrans4<<<dim3(16, 16, 4), blk, 0, stream>>>(Wq, Wk, Wv, Wo, Wtall);
  gemm_qkv<<<dim3(DM/128, NTOK/128, 3), blk, 0, stream>>>(
      Aq, Ak, Av, Wtall, bq, bk, bv, Qb, Kb, Vt);
  attn_stats<<<dim3(SEQ/64, NH*2), blk, 0, stream>>>(Qb, Kb, Vt);
  attn_pv<<<dim3(SEQ/128, NH*2), blk, 0, stream>>>(Qb, Kb, Vt, Xb);
  gemm_o<<<dim3(DM/128, NTOK/128), blk, 0, stream>>>(
      Xb, Wtall + 3*(size_t)DM*DM, bo, out);
}